// Round 9
// baseline (252.549 us; speedup 1.0000x reference)
//
#include <hip/hip_runtime.h>
#include <cstddef>
#include <cstdint>

#define SCALE_WEIGHT 0.70710678118654752440f

static constexpr int B_ = 8, C_ = 512, T_ = 2048, S_ = 2048;
static constexpr size_t BCT_ = (size_t)B_ * C_ * T_;   // 8.4M  (ctx region elems)
static constexpr size_t BTS_ = (size_t)B_ * T_ * S_;   // 33.5M (attn region elems)

typedef _Float16 half_t;
typedef half_t half8  __attribute__((ext_vector_type(8)));
typedef half_t half4v __attribute__((ext_vector_type(4)));
typedef float  floatx4 __attribute__((ext_vector_type(4)));

// async global->LDS, 16B per lane. LDS dest = wave-uniform base + lane*16.
__device__ __forceinline__ void gload_lds16(const void* g, void* l) {
    __builtin_amdgcn_global_load_lds(
        (const __attribute__((address_space(1))) void*)g,
        (__attribute__((address_space(3))) void*)l, 16, 0, 0);
}

// ---------------------------------------------------------------------------
// merged pre-pass: z<16 -> 64x64 transpose+convert of x/top; z==16 -> flat
// f32->f16 convert of comb and W (grid-stride over the plane's 256 blocks).
// ---------------------------------------------------------------------------
__global__ __launch_bounds__(256) void pre_kernel(
    const float* __restrict__ x, const float* __restrict__ top,
    const float* __restrict__ comb, const float* __restrict__ W,
    half_t* __restrict__ xT, half_t* __restrict__ topT,
    half_t* __restrict__ combh, half_t* __restrict__ Wh)
{
    const int z = blockIdx.z;
    if (z < 16) {
        __shared__ float tile[64][65];
        const float* in = (z < 8) ? x : top;
        half_t* outp = (z < 8) ? xT : topT;
        const int b  = z & 7;
        const int r0 = blockIdx.y * 64, c0 = blockIdx.x * 64;
        const float* ib = in + (size_t)b * C_ * T_;
        half_t* ob = outp + (size_t)b * C_ * T_;
        const int t  = threadIdx.x;
        const int rr = t >> 4, cq = t & 15;
        #pragma unroll
        for (int i = 0; i < 4; ++i) {
            const int r = rr + i * 16;
            float4 v = *(const float4*)&ib[(size_t)(r0 + r) * T_ + c0 + cq * 4];
            tile[cq * 4 + 0][r] = v.x;
            tile[cq * 4 + 1][r] = v.y;
            tile[cq * 4 + 2][r] = v.z;
            tile[cq * 4 + 3][r] = v.w;
        }
        __syncthreads();
        const int cw = t >> 4, rq = (t & 15) * 4;
        #pragma unroll
        for (int i = 0; i < 4; ++i) {
            const int c = cw + i * 16;
            half4v h = {(half_t)tile[c][rq + 0], (half_t)tile[c][rq + 1],
                        (half_t)tile[c][rq + 2], (half_t)tile[c][rq + 3]};
            *(half4v*)&ob[(size_t)(c0 + c) * C_ + r0 + rq] = h;
        }
    } else {
        const int n4a = (int)((size_t)B_ * C_ * S_ / 4);
        const int n4tot = n4a + C_ * C_ / 4;
        const int planeT = 32 * 8 * 256;
        for (int i = (blockIdx.y * 32 + blockIdx.x) * 256 + threadIdx.x;
             i < n4tot; i += planeT) {
            const float4* src; half4v* dst; int j;
            if (i < n4a) { src = (const float4*)comb; dst = (half4v*)combh; j = i; }
            else         { src = (const float4*)W;    dst = (half4v*)Wh;    j = i - n4a; }
            float4 v = src[j];
            dst[j] = (half4v){(half_t)v.x, (half_t)v.y, (half_t)v.z, (half_t)v.w};
        }
    }
}

// ---------------------------------------------------------------------------
// R3-proven MFMA fp16 GEMM engine: 128x128 tile, 4 waves (64x64 each), BK=64,
// double-buffered LDS, counted vmcnt(8), 2 barriers per K-tile. Plain dim3
// grid (x = n-tile fastest, z = batch) exactly as R3 measured fast.
// A: [M][K] f16 k-contig.  B: [N][K] f16 k-contig.
// EPI 0 (K1): f16 store of (acc + bias[col] + base[b][col][row])*SCALE
// EPI 1 (k2p): per-128-col-tile softmax prep: p = exp(l - m_tile) f16 via
//              LDS-staged coalesced stores + (m, sigma) per-row stats
// EPI 2 (K4s): B-fragments scaled by f[b][st][n] (LDS-staged); f32 C store
// ---------------------------------------------------------------------------
template<int MM, int NN, int KK, int EPI>
__global__ __launch_bounds__(256) void gemm64_kernel(
    const half_t* __restrict__ A, const half_t* __restrict__ Bm,
    size_t sA, size_t sB,
    float* __restrict__ outF, half_t* __restrict__ outH,
    const float* __restrict__ base, const float* __restrict__ bias,
    float* __restrict__ mArr, float* __restrict__ sArr,
    const float* __restrict__ fArr)
{
    constexpr int NT = KK >> 6;
    constexpr int LDSSZ = (EPI == 1) ? 67584 : ((EPI == 2) ? 73728 : 65536);
    __shared__ __align__(128) char smem[LDSSZ];
    // As slots @ 0,16K ; Bs slots @ 32K,48K ; EPI1 stats @64K ; EPI2 f @64K

    const int tid  = threadIdx.x;
    const int lane = tid & 63, w = tid >> 6;
    const int wr = w >> 1, wc = w & 1;

    // plain dim3 grid (R3 style)
    const int b  = blockIdx.z;
    const int m0 = blockIdx.y * 128, n0 = blockIdx.x * 128;

    const half_t* Ab = A  + (size_t)b * sA;
    const half_t* Bb = Bm + (size_t)b * sB;

    // staging: wave w owns rows [w*32, w*32+32), 4 chunks of 8 rows
    const int lr = lane >> 3;            // row within chunk (0..7)
    const int sw = (lane & 7) ^ lr;      // swizzled source k-group
    const half_t* aG[4]; const half_t* bG[4];
    int dOff[4];
    #pragma unroll
    for (int i = 0; i < 4; ++i) {
        const int r = w * 32 + i * 8 + lr;
        aG[i] = Ab + (size_t)(m0 + r) * KK + sw * 8;
        bG[i] = Bb + (size_t)(n0 + r) * KK + sw * 8;
        dOff[i] = (w * 32 + i * 8) * 128;
    }

    // fragment ds_read byte offsets (kk=1 half is addr ^ 64)
    const int fr = lane & 15, kg = lane >> 4, q4 = kg * 4;
    int aoff[4], boff[4];
    #pragma unroll
    for (int mi = 0; mi < 4; ++mi) {
        const int m = wr * 64 + mi * 16 + fr;
        aoff[mi] = m * 128 + ((kg ^ (m & 7)) << 4);
    }
    #pragma unroll
    for (int nj = 0; nj < 4; ++nj) {
        const int n = wc * 64 + nj * 16 + fr;
        boff[nj] = n * 128 + ((kg ^ (n & 7)) << 4);
    }

    floatx4 acc[4][4];
    #pragma unroll
    for (int mi = 0; mi < 4; ++mi)
        #pragma unroll
        for (int nj = 0; nj < 4; ++nj)
            acc[mi][nj] = (floatx4){0.f, 0.f, 0.f, 0.f};

    auto STAGE = [&](int t, int pg) {
        const int k0 = t * 64;
        char* Ad = smem + pg * 16384;
        char* Bd = smem + 32768 + pg * 16384;
        #pragma unroll
        for (int i = 0; i < 4; ++i) {
            gload_lds16(aG[i] + k0, Ad + dOff[i]);
            gload_lds16(bG[i] + k0, Bd + dOff[i]);
        }
    };

    auto COMPUTE = [&](int pg, int t) {
        const char* Ar = smem + pg * 16384;
        const char* Br = smem + 32768 + pg * 16384;
        #pragma unroll
        for (int kk = 0; kk < 2; ++kk) {
            half8 af[4], bf[4];
            #pragma unroll
            for (int mi = 0; mi < 4; ++mi)
                af[mi] = *(const half8*)(Ar + (aoff[mi] ^ (kk << 6)));
            #pragma unroll
            for (int nj = 0; nj < 4; ++nj)
                bf[nj] = *(const half8*)(Br + (boff[nj] ^ (kk << 6)));
            if constexpr (EPI == 2) {
                const float* fls = (const float*)(smem + 65536);
                const int st = t >> 1;    // 128-wide s-tile of this K-chunk
                #pragma unroll
                for (int nj = 0; nj < 4; ++nj) {
                    const half_t fh = (half_t)fls[st * 128 + wc * 64 + nj * 16 + fr];
                    #pragma unroll
                    for (int e = 0; e < 8; ++e) bf[nj][e] *= fh;
                }
            }
            #pragma unroll
            for (int mi = 0; mi < 4; ++mi)
                #pragma unroll
                for (int nj = 0; nj < 4; ++nj)
                    acc[mi][nj] = __builtin_amdgcn_mfma_f32_16x16x32_f16(
                        af[mi], bf[nj], acc[mi][nj], 0, 0, 0);
        }
    };

    // prologue
    if constexpr (EPI == 2) {
        // stage f[b][16][n0..n0+128) f32 = 8KB -> smem+64K (uniform across waves
        // so per-wave vmcnt counting stays exact; drained by first vmcnt(8))
        const float* fB = fArr + (size_t)b * 16 * NN;
        #pragma unroll
        for (int c = 0; c < 8; ++c)
            gload_lds16(fB + (size_t)(2 * c + (lane >> 5)) * NN + n0 + (lane & 31) * 4,
                        smem + 65536 + c * 1024);
    }
    STAGE(0, 0);
    int cur = 0;
    #pragma unroll 1
    for (int t = 0; t < NT - 1; ++t) {
        STAGE(t + 1, cur ^ 1);
        asm volatile("s_waitcnt vmcnt(8)" ::: "memory");   // tile-t loads done
        __builtin_amdgcn_s_barrier();
        __builtin_amdgcn_sched_barrier(0);
        COMPUTE(cur, t);
        asm volatile("s_waitcnt lgkmcnt(0)" ::: "memory"); // ds_reads complete
        __builtin_amdgcn_sched_barrier(0);
        __builtin_amdgcn_s_barrier();                      // buf free to overwrite
        __builtin_amdgcn_sched_barrier(0);
        cur ^= 1;
    }
    asm volatile("s_waitcnt vmcnt(0)" ::: "memory");
    __builtin_amdgcn_s_barrier();
    __builtin_amdgcn_sched_barrier(0);
    COMPUTE(cur, NT - 1);

    // ------------------------------- epilogues -------------------------------
    if constexpr (EPI == 0) {
        half_t* Cb = outH + (size_t)b * ((size_t)MM * NN);
        #pragma unroll
        for (int nj = 0; nj < 4; ++nj) {
            const int col = n0 + wc * 64 + nj * 16 + fr;
            const float bn = bias[col];
            const float* bp = base + ((size_t)b * NN + col) * (size_t)MM;
            #pragma unroll
            for (int mi = 0; mi < 4; ++mi) {
                const int row = m0 + wr * 64 + mi * 16 + q4;
                #pragma unroll
                for (int r = 0; r < 4; ++r) {
                    float v = (acc[mi][nj][r] + bn + bp[row + r]) * SCALE_WEIGHT;
                    Cb[(size_t)(row + r) * NN + col] = (half_t)v;
                }
            }
        }
    } else if constexpr (EPI == 2) {
        float* Cb = outF + (size_t)b * ((size_t)MM * NN);
        #pragma unroll
        for (int mi = 0; mi < 4; ++mi) {
            const int row = m0 + wr * 64 + mi * 16 + q4;
            #pragma unroll
            for (int nj = 0; nj < 4; ++nj) {
                const int col = n0 + wc * 64 + nj * 16 + fr;
                #pragma unroll
                for (int r = 0; r < 4; ++r)
                    Cb[(size_t)(row + r) * NN + col] = acc[mi][nj][r];
            }
        }
    } else {
        // k2p: tile row-max, p=exp(l-m) -> XOR-swizzled LDS tile (reusing the
        // dead ring), stats out, then coalesced half8 global stores.
        __syncthreads();                       // all waves' frag reads consumed
        float* rmax = (float*)(smem + 65536);  // [2][128]
        float* rsum = (float*)(smem + 66560);  // [2][128]

        #pragma unroll
        for (int mi = 0; mi < 4; ++mi)
            #pragma unroll
            for (int r = 0; r < 4; ++r) {
                float v = fmaxf(fmaxf(acc[mi][0][r], acc[mi][1][r]),
                                fmaxf(acc[mi][2][r], acc[mi][3][r]));
                v = fmaxf(v, __shfl_xor(v, 1));
                v = fmaxf(v, __shfl_xor(v, 2));
                v = fmaxf(v, __shfl_xor(v, 4));
                v = fmaxf(v, __shfl_xor(v, 8));
                if (fr == 0) rmax[wc * 128 + wr * 64 + mi * 16 + q4 + r] = v;
            }
        __syncthreads();

        #pragma unroll
        for (int mi = 0; mi < 4; ++mi)
            #pragma unroll
            for (int r = 0; r < 4; ++r) {
                const int row = wr * 64 + mi * 16 + q4 + r;
                const float mC = fmaxf(rmax[row], rmax[128 + row]);
                float s = 0.f;
                #pragma unroll
                for (int nj = 0; nj < 4; ++nj) {
                    const int col = wc * 64 + nj * 16 + fr;
                    float pv = __expf(acc[mi][nj][r] - mC);
                    s += pv;
                    *(half_t*)(smem + row * 256 + ((col * 2) ^ ((row & 7) << 4))) =
                        (half_t)pv;
                }
                s += __shfl_xor(s, 1);
                s += __shfl_xor(s, 2);
                s += __shfl_xor(s, 4);
                s += __shfl_xor(s, 8);
                if (fr == 0) rsum[wc * 128 + row] = s;
            }
        __syncthreads();

        if (tid < 128) {
            const float m = fmaxf(rmax[tid], rmax[128 + tid]);
            const float s = rsum[tid] + rsum[128 + tid];
            const size_t si = ((size_t)(b * 16 + (n0 >> 7))) * (size_t)MM + m0 + tid;
            mArr[si] = m;
            sArr[si] = s;
        }

        const int prow = tid >> 1, ph = tid & 1;
        half_t* Pb = outH + ((size_t)b * MM + m0 + prow) * (size_t)NN + n0 + ph * 64;
        #pragma unroll
        for (int j = 0; j < 8; ++j) {
            half8 v = *(const half8*)(smem + prow * 256 +
                                      ((ph * 128 + j * 16) ^ ((prow & 7) << 4)));
            *(half8*)&Pb[j * 8] = v;
        }
    }
}

// ---------------------------------------------------------------------------
// kf: f[b][st][t] = exp(m_st - m_fin) / sigma  (exact tile-stat combine)
// ---------------------------------------------------------------------------
__global__ __launch_bounds__(256) void kf_kernel(
    const float* __restrict__ mArr, const float* __restrict__ sArr,
    float* __restrict__ fArr)
{
    const int gid = blockIdx.x * 256 + threadIdx.x;   // b*2048 + t
    const int b = gid >> 11, t = gid & 2047;
    float mv[16];
    float mfin = -3.0e38f;
    #pragma unroll
    for (int j = 0; j < 16; ++j) {
        mv[j] = mArr[((size_t)(b * 16 + j)) * T_ + t];
        mfin = fmaxf(mfin, mv[j]);
    }
    float sig = 0.f;
    #pragma unroll
    for (int j = 0; j < 16; ++j)
        sig += sArr[((size_t)(b * 16 + j)) * T_ + t] * __expf(mv[j] - mfin);
    const float inv = 1.f / sig;
    #pragma unroll
    for (int j = 0; j < 16; ++j)
        fArr[((size_t)(b * 16 + j)) * T_ + t] = __expf(mv[j] - mfin) * inv;
}

// ---------------------------------------------------------------------------
// k3n: attnf[b][t][s] = p[b][t][s] * f[b][s>>7][t]   (f32 attn output)
// ---------------------------------------------------------------------------
__global__ __launch_bounds__(256) void k3n_kernel(
    const half_t* __restrict__ P, const float* __restrict__ fArr,
    float* __restrict__ attnf)
{
    const int bid = blockIdx.x;           // b*2048 + t
    const int b = bid >> 11, t = bid & 2047;
    const int tid = threadIdx.x;
    const float f = fArr[((size_t)(b * 16 + (tid >> 4))) * T_ + t];
    const size_t rb = (size_t)bid * S_ + tid * 8;
    half8 v = *(const half8*)&P[rb];
    float4 o0 = {(float)v[0] * f, (float)v[1] * f, (float)v[2] * f, (float)v[3] * f};
    float4 o1 = {(float)v[4] * f, (float)v[5] * f, (float)v[6] * f, (float)v[7] * f};
    *(float4*)&attnf[rb]     = o0;
    *(float4*)&attnf[rb + 4] = o1;
}

extern "C" void kernel_launch(void* const* d_in, const int* in_sizes, int n_in,
                              void* d_out, int out_size, void* d_ws, size_t ws_size,
                              hipStream_t stream) {
    const float* base = (const float*)d_in[0];  // [B,C,T,1]
    const float* x    = (const float*)d_in[1];  // [B,C,T,1]
    const float* top  = (const float*)d_in[2];  // [B,C,S]
    const float* comb = (const float*)d_in[3];  // [B,C,S]
    const float* W    = (const float*)d_in[4];  // [C,C]
    const float* bias = (const float*)d_in[5];  // [C]

    float* out   = (float*)d_out;
    float* ctx   = out;          // [B,C,T] final context output (f32, 33.5MB)
    float* attnf = out + BCT_;   // [B,T,S] attn output (f32, 134MB)

    // fp16 staging overlaid on the ctx region (dead before K4s rewrites it):
    half_t* xT   = (half_t*)d_out;        // [B][T][C] f16
    half_t* topT = xT + BCT_;             // [B][S][C] f16

    // ws layout (~104MB):
    half_t* pws   = (half_t*)d_ws;                    // [B][T][S] f16, 67MB
    half_t* combh = pws + BTS_;                       // [B][C][S] f16, 16.8MB
    half_t* Wh    = combh + (size_t)B_ * C_ * S_;     // [C][C] f16, 0.5MB
    half_t* tgtT  = Wh + (size_t)C_ * C_;             // [B][T][C] f16, 16.8MB
    float*  mArr  = (float*)(tgtT + BCT_);            // [B][16][T] f32, 1MB
    float*  sArr  = mArr + (size_t)B_ * 16 * T_;      // [B][16][T] f32, 1MB
    float*  fArr  = sArr + (size_t)B_ * 16 * T_;      // [B][16][T] f32, 1MB

    // pre-pass (1 launch): transposes + converts
    pre_kernel<<<dim3(32, 8, 17), 256, 0, stream>>>(
        x, top, comb, W, xT, topT, combh, Wh);

    // K1: tgtT[b][t][o] = (x^T W^T + b + base)*SCALE   M=T,N=C,K=C (sB=0)
    gemm64_kernel<2048, 512, 512, 0><<<dim3(C_ / 128, T_ / 128, B_), 256, 0, stream>>>(
        xT, Wh, (size_t)T_ * C_, 0,
        nullptr, tgtT, base, bias, nullptr, nullptr, nullptr);

    // k2p: p = exp(logits - m_tile) f16 + per-128-tile stats   M=T,N=S,K=C
    gemm64_kernel<2048, 2048, 512, 1><<<dim3(S_ / 128, T_ / 128, B_), 256, 0, stream>>>(
        tgtT, topT, (size_t)T_ * C_, (size_t)S_ * C_,
        nullptr, pws, nullptr, nullptr, mArr, sArr, nullptr);

    // kf: exact stat combine -> f[b][st][t]
    kf_kernel<<<64, 256, 0, stream>>>(mArr, sArr, fArr);

    // k3n: attnf = p * f  (f32 attn output)
    k3n_kernel<<<B_ * T_, 256, 0, stream>>>(pws, fArr, attnf);

    // K4s: ctx[b][c][t] = sum_s comb[c][s] * (p[t][s]*f[st][t])  M=C,N=T,K=S
    gemm64_kernel<512, 2048, 2048, 2><<<dim3(T_ / 128, C_ / 128, B_), 256, 0, stream>>>(
        combh, pws, (size_t)C_ * S_, (size_t)T_ * S_,
        ctx, nullptr, nullptr, nullptr, nullptr, nullptr, fArr);
}

// Round 10
// 215.670 us; speedup vs baseline: 1.1710x; 1.1710x over previous
//
#include <hip/hip_runtime.h>
#include <cstddef>
#include <cstdint>

#define SCALE_WEIGHT 0.70710678118654752440f

static constexpr int B_ = 8, C_ = 512, T_ = 2048, S_ = 2048;
static constexpr size_t BCT_ = (size_t)B_ * C_ * T_;   // 8.4M  (ctx region elems)
static constexpr size_t BTS_ = (size_t)B_ * T_ * S_;   // 33.5M (attn region elems)

typedef _Float16 half_t;
typedef half_t half8  __attribute__((ext_vector_type(8)));
typedef half_t half4v __attribute__((ext_vector_type(4)));
typedef float  floatx4 __attribute__((ext_vector_type(4)));

// async global->LDS, 16B per lane. LDS dest = wave-uniform base + lane*16.
__device__ __forceinline__ void gload_lds16(const void* g, void* l) {
    __builtin_amdgcn_global_load_lds(
        (const __attribute__((address_space(1))) void*)g,
        (__attribute__((address_space(3))) void*)l, 16, 0, 0);
}

// ---------------------------------------------------------------------------
// merged pre-pass: z<16 -> 64x64 transpose+convert of x/top; z==16 -> flat
// f32->f16 convert of comb and W (grid-stride over the plane's 256 blocks).
// (proven harmless R6-R9; replaces 4 launches with 1)
// ---------------------------------------------------------------------------
__global__ __launch_bounds__(256) void pre_kernel(
    const float* __restrict__ x, const float* __restrict__ top,
    const float* __restrict__ comb, const float* __restrict__ W,
    half_t* __restrict__ xT, half_t* __restrict__ topT,
    half_t* __restrict__ combh, half_t* __restrict__ Wh)
{
    const int z = blockIdx.z;
    if (z < 16) {
        __shared__ float tile[64][65];
        const float* in = (z < 8) ? x : top;
        half_t* outp = (z < 8) ? xT : topT;
        const int b  = z & 7;
        const int r0 = blockIdx.y * 64, c0 = blockIdx.x * 64;
        const float* ib = in + (size_t)b * C_ * T_;
        half_t* ob = outp + (size_t)b * C_ * T_;
        const int t  = threadIdx.x;
        const int rr = t >> 4, cq = t & 15;
        #pragma unroll
        for (int i = 0; i < 4; ++i) {
            const int r = rr + i * 16;
            float4 v = *(const float4*)&ib[(size_t)(r0 + r) * T_ + c0 + cq * 4];
            tile[cq * 4 + 0][r] = v.x;
            tile[cq * 4 + 1][r] = v.y;
            tile[cq * 4 + 2][r] = v.z;
            tile[cq * 4 + 3][r] = v.w;
        }
        __syncthreads();
        const int cw = t >> 4, rq = (t & 15) * 4;
        #pragma unroll
        for (int i = 0; i < 4; ++i) {
            const int c = cw + i * 16;
            half4v h = {(half_t)tile[c][rq + 0], (half_t)tile[c][rq + 1],
                        (half_t)tile[c][rq + 2], (half_t)tile[c][rq + 3]};
            *(half4v*)&ob[(size_t)(c0 + c) * C_ + r0 + rq] = h;
        }
    } else {
        const int n4a = (int)((size_t)B_ * C_ * S_ / 4);
        const int n4tot = n4a + C_ * C_ / 4;
        const int planeT = 32 * 8 * 256;
        for (int i = (blockIdx.y * 32 + blockIdx.x) * 256 + threadIdx.x;
             i < n4tot; i += planeT) {
            const float4* src; half4v* dst; int j;
            if (i < n4a) { src = (const float4*)comb; dst = (half4v*)combh; j = i; }
            else         { src = (const float4*)W;    dst = (half4v*)Wh;    j = i - n4a; }
            float4 v = src[j];
            dst[j] = (half4v){(half_t)v.x, (half_t)v.y, (half_t)v.z, (half_t)v.w};
        }
    }
}

// ---------------------------------------------------------------------------
// R3-exact MFMA fp16 GEMM: 128x128 tile, 4 waves (64x64 each), BK=64,
// double-buffered LDS, counted vmcnt(8), 2 barriers per K-tile. Full loop
// unroll (compile-time cur). Measured: ~690 TF effective at these shapes.
// A: [M][K] f16 k-contig.  B: [N][K] f16 k-contig.  C: [M][N].
// EPI 0: f32 store.  EPI 1 (K1): f16 store of (acc + bias[n] + base[b][n][m])*SCALE.
// ---------------------------------------------------------------------------
template<int EPI>
__global__ __launch_bounds__(256) void gemm_f16_db_kernel(
    const half_t* __restrict__ A, const half_t* __restrict__ Bm,
    float* __restrict__ Cout, half_t* __restrict__ CoutH,
    const float* __restrict__ base, const float* __restrict__ bias,
    int M, int N, int K, size_t sA, size_t sB, size_t sC)
{
    __shared__ __align__(128) half_t As[2][128 * 64];
    __shared__ __align__(128) half_t Bs[2][128 * 64];

    const int tid  = threadIdx.x;
    const int lane = tid & 63, w = tid >> 6;
    const int wr = w >> 1, wc = w & 1;
    const int b  = blockIdx.z;
    const int m0 = blockIdx.y * 128, n0 = blockIdx.x * 128;

    const half_t* Ab = A  + (size_t)b * sA;
    const half_t* Bb = Bm + (size_t)b * sB;

    const int lr = lane >> 3;
    const int sw = (lane & 7) ^ lr;
    const half_t* aG[4]; const half_t* bG[4];
    int dOff[4];
    #pragma unroll
    for (int i = 0; i < 4; ++i) {
        const int r = w * 32 + i * 8 + lr;
        aG[i] = Ab + (size_t)(m0 + r) * K + sw * 8;
        bG[i] = Bb + (size_t)(n0 + r) * K + sw * 8;
        dOff[i] = (w * 32 + i * 8) * 128;
    }

    const int fr = lane & 15, kg = lane >> 4;
    int aoff[4], boff[4];
    #pragma unroll
    for (int mi = 0; mi < 4; ++mi) {
        const int m = wr * 64 + mi * 16 + fr;
        aoff[mi] = m * 128 + ((kg ^ (m & 7)) << 4);
    }
    #pragma unroll
    for (int nj = 0; nj < 4; ++nj) {
        const int n = wc * 64 + nj * 16 + fr;
        boff[nj] = n * 128 + ((kg ^ (n & 7)) << 4);
    }

    floatx4 acc[4][4];
    #pragma unroll
    for (int mi = 0; mi < 4; ++mi)
        #pragma unroll
        for (int nj = 0; nj < 4; ++nj)
            acc[mi][nj] = (floatx4){0.f, 0.f, 0.f, 0.f};

    auto STAGE = [&](int t, int pg) {
        const int k0 = t * 64;
        char* Ad = (char*)As[pg];
        char* Bd = (char*)Bs[pg];
        #pragma unroll
        for (int i = 0; i < 4; ++i) {
            gload_lds16(aG[i] + k0, Ad + dOff[i]);
            gload_lds16(bG[i] + k0, Bd + dOff[i]);
        }
    };

    auto COMPUTE = [&](int pg) {
        const char* Ar = (const char*)As[pg];
        const char* Br = (const char*)Bs[pg];
        #pragma unroll
        for (int kk = 0; kk < 2; ++kk) {
            half8 af[4], bf[4];
            #pragma unroll
            for (int mi = 0; mi < 4; ++mi)
                af[mi] = *(const half8*)(Ar + (aoff[mi] ^ (kk << 6)));
            #pragma unroll
            for (int nj = 0; nj < 4; ++nj)
                bf[nj] = *(const half8*)(Br + (boff[nj] ^ (kk << 6)));
            #pragma unroll
            for (int mi = 0; mi < 4; ++mi)
                #pragma unroll
                for (int nj = 0; nj < 4; ++nj)
                    acc[mi][nj] = __builtin_amdgcn_mfma_f32_16x16x32_f16(
                        af[mi], bf[nj], acc[mi][nj], 0, 0, 0);
        }
    };

    const int NT = K >> 6;
    STAGE(0, 0);
    int cur = 0;
    for (int t = 0; t < NT - 1; ++t) {
        STAGE(t + 1, cur ^ 1);
        asm volatile("s_waitcnt vmcnt(8)" ::: "memory");
        __builtin_amdgcn_s_barrier();
        __builtin_amdgcn_sched_barrier(0);
        COMPUTE(cur);
        asm volatile("s_waitcnt lgkmcnt(0)" ::: "memory");
        __builtin_amdgcn_sched_barrier(0);
        __builtin_amdgcn_s_barrier();
        __builtin_amdgcn_sched_barrier(0);
        cur ^= 1;
    }
    asm volatile("s_waitcnt vmcnt(0)" ::: "memory");
    __builtin_amdgcn_s_barrier();
    __builtin_amdgcn_sched_barrier(0);
    COMPUTE(cur);

    if constexpr (EPI == 0) {
        float* Cb = Cout + (size_t)b * sC;
        #pragma unroll
        for (int mi = 0; mi < 4; ++mi) {
            const int row = m0 + wr * 64 + mi * 16 + (lane >> 4) * 4;
            #pragma unroll
            for (int nj = 0; nj < 4; ++nj) {
                const int col = n0 + wc * 64 + nj * 16 + (lane & 15);
                #pragma unroll
                for (int r = 0; r < 4; ++r)
                    Cb[(size_t)(row + r) * N + col] = acc[mi][nj][r];
            }
        }
    } else {
        half_t* Cb = CoutH + (size_t)b * sC;
        #pragma unroll
        for (int nj = 0; nj < 4; ++nj) {
            const int col = n0 + wc * 64 + nj * 16 + (lane & 15);
            const float bn = bias[col];
            const float* bp = base + ((size_t)b * N + col) * (size_t)M;
            #pragma unroll
            for (int mi = 0; mi < 4; ++mi) {
                const int row = m0 + wr * 64 + mi * 16 + (lane >> 4) * 4;
                #pragma unroll
                for (int r = 0; r < 4; ++r) {
                    float v = (acc[mi][nj][r] + bn + bp[row + r]) * SCALE_WEIGHT;
                    Cb[(size_t)(row + r) * N + col] = (half_t)v;
                }
            }
        }
    }
}

// ---------------------------------------------------------------------------
// row softmax over S, in-place f32 + fp16 copy for the K4 MFMA operand
// ---------------------------------------------------------------------------
__global__ __launch_bounds__(256) void k3_softmax_kernel(
    float* __restrict__ logits, half_t* __restrict__ attnh)
{
    float* p = logits + (size_t)blockIdx.x * S_;
    half4v* ph = (half4v*)(attnh + (size_t)blockIdx.x * S_);
    const int tid = threadIdx.x;
    float4 v0 = *(const float4*)&p[tid * 4];
    float4 v1 = *(const float4*)&p[tid * 4 + 1024];

    float mx = fmaxf(fmaxf(fmaxf(v0.x, v0.y), fmaxf(v0.z, v0.w)),
                     fmaxf(fmaxf(v1.x, v1.y), fmaxf(v1.z, v1.w)));
    #pragma unroll
    for (int off = 32; off; off >>= 1)
        mx = fmaxf(mx, __shfl_xor(mx, off));

    __shared__ float sm[4];
    __shared__ float ss[4];
    const int wid = tid >> 6, lane = tid & 63;
    if (lane == 0) sm[wid] = mx;
    __syncthreads();
    const float rmax = fmaxf(fmaxf(sm[0], sm[1]), fmaxf(sm[2], sm[3]));

    float e[8];
    e[0] = __expf(v0.x - rmax); e[1] = __expf(v0.y - rmax);
    e[2] = __expf(v0.z - rmax); e[3] = __expf(v0.w - rmax);
    e[4] = __expf(v1.x - rmax); e[5] = __expf(v1.y - rmax);
    e[6] = __expf(v1.z - rmax); e[7] = __expf(v1.w - rmax);

    float sum = 0.f;
    #pragma unroll
    for (int i = 0; i < 8; ++i) sum += e[i];
    #pragma unroll
    for (int off = 32; off; off >>= 1)
        sum += __shfl_xor(sum, off);
    if (lane == 0) ss[wid] = sum;
    __syncthreads();
    const float inv = 1.f / (ss[0] + ss[1] + ss[2] + ss[3]);

    float4 r0, r1;
    r0.x = e[0] * inv; r0.y = e[1] * inv; r0.z = e[2] * inv; r0.w = e[3] * inv;
    r1.x = e[4] * inv; r1.y = e[5] * inv; r1.z = e[6] * inv; r1.w = e[7] * inv;
    *(float4*)&p[tid * 4] = r0;
    *(float4*)&p[tid * 4 + 1024] = r1;
    ph[tid]       = (half4v){(half_t)r0.x, (half_t)r0.y, (half_t)r0.z, (half_t)r0.w};
    ph[tid + 256] = (half4v){(half_t)r1.x, (half_t)r1.y, (half_t)r1.z, (half_t)r1.w};
}

extern "C" void kernel_launch(void* const* d_in, const int* in_sizes, int n_in,
                              void* d_out, int out_size, void* d_ws, size_t ws_size,
                              hipStream_t stream) {
    const float* base = (const float*)d_in[0];  // [B,C,T,1]
    const float* x    = (const float*)d_in[1];  // [B,C,T,1]
    const float* top  = (const float*)d_in[2];  // [B,C,S]
    const float* comb = (const float*)d_in[3];  // [B,C,S]
    const float* W    = (const float*)d_in[4];  // [C,C]
    const float* bias = (const float*)d_in[5];  // [C]

    float* out    = (float*)d_out;
    float* ctx    = out;          // [B,C,T] final context output (f32)
    float* logits = out + BCT_;   // [B,T,S] logits -> attn output (f32)

    // fp16 staging in the ctx region of d_out (dead before K4 rewrites it):
    half_t* xT   = (half_t*)d_out;        // [B][T][C] f16
    half_t* topT = xT + BCT_;             // [B][S][C] f16

    // ws: attnh [B][T][S] f16 (67MB, tgtT aliases its head — dead before K3),
    //     combh [B][C][S] f16 (16.8MB), Wh [C][C] f16 (0.5MB).
    half_t* attnh = (half_t*)d_ws;
    half_t* tgtT  = attnh;                       // [B][T][C] f16, alias (see above)
    half_t* combh = attnh + BTS_;
    half_t* Wh    = combh + (size_t)B_ * C_ * S_;

    // pre-pass (1 launch): both transposes + both converts
    pre_kernel<<<dim3(32, 8, 17), 256, 0, stream>>>(
        x, top, comb, W, xT, topT, combh, Wh);

    // K1: tgtT[b][t][o] = (x^T W^T + b + base)*SCALE   M=T,N=C,K=C, sB=0 (shared W)
    gemm_f16_db_kernel<1><<<dim3(C_ / 128, T_ / 128, B_), 256, 0, stream>>>(
        xT, Wh, nullptr, tgtT, base, bias,
        T_, C_, C_, (size_t)T_ * C_, 0, (size_t)T_ * C_);

    // K2: logits[b][t][s] = tgtT . topT                M=T,N=S,K=C
    gemm_f16_db_kernel<0><<<dim3(S_ / 128, T_ / 128, B_), 256, 0, stream>>>(
        tgtT, topT, logits, nullptr, nullptr, nullptr,
        T_, S_, C_, (size_t)T_ * C_, (size_t)S_ * C_, (size_t)T_ * S_);

    // K3: softmax rows, write f32 attn (output) + f16 attn (K4 operand)
    k3_softmax_kernel<<<dim3(B_ * T_), 256, 0, stream>>>(logits, attnh);

    // K4: ctx[b][c][t] = combh . attnh                 M=C,N=T,K=S
    gemm_f16_db_kernel<0><<<dim3(T_ / 128, C_ / 128, B_), 256, 0, stream>>>(
        combh, attnh, ctx, nullptr, nullptr, nullptr,
        C_, T_, S_, (size_t)C_ * S_, (size_t)T_ * S_, (size_t)C_ * T_);
}